// Round 23
// baseline (43.715 us; speedup 1.0000x reference)
//
#include <hip/hip_runtime.h>
#include <stdint.h>

#define NBITS 4096
#define NROWS 2048
#define CHUNK 16
#define TBLG  128
#define TBLE  129              // entries per xy case
#define NTAB  (4 * TBLE)       // 516
#define TBLN  (NTAB * 2)       // 1032 floats (~4.1 KB)

__device__ __forceinline__ float sigmoidf_(float z) {
  return 1.0f / (1.0f + __expf(-z));
}

// Single fused kernel (proven structure from round 20) + coalesced I/O.
// block = one row (256 threads); thread = one 16-bit chunk.
// Phase 1: coalesced load + 2-bit pack into 1KB LDS code array.
// Phase 2: per-block LDS table build (4x129 MLP collapse).
// Phase 3: per-thread serial scan (warm-up 16 + real 16) via LDS table lerp.
// Phase 4: stage outputs in LDS row, coalesced global store.
__global__ __launch_bounds__(256) void awc_scan(
    const float* __restrict__ x, const float* __restrict__ y,
    const float* __restrict__ W1, const float* __restrict__ b1,
    const float* __restrict__ W2, const float* __restrict__ b2,
    float* __restrict__ out) {
  __shared__ float    sW1[96], sb1[32], sW2[64], sb2[2];
  __shared__ float    T[TBLN];     // interleaved (Tc, To) pairs
  __shared__ uint32_t sCode[260];  // 256 dwords of 2-bit codes (+pad for c==0 warm read)
  __shared__ float    fRow[NBITS]; // 16 KB output staging

  const int tid = threadIdx.x;
  const int r = blockIdx.x;

  // ---- phase 1: coalesced load, pack col j -> bits 2j (x bit | y bit<<1) ----
  {
    const float4* x4 = (const float4*)(x + (size_t)r * NBITS);
    const float4* y4 = (const float4*)(y + (size_t)r * NBITS);
    uint8_t* sBytes = (uint8_t*)sCode;
    #pragma unroll
    for (int q = 0; q < 4; ++q) {
      int F = tid + 256 * q;                 // float4 index: lanes consecutive -> coalesced
      float4 xv = x4[F], yv = y4[F];
      uint32_t code =  (xv.x > 0.5f ? 1u : 0u) | (yv.x > 0.5f ? 2u : 0u);
      code |= ((xv.y > 0.5f ? 1u : 0u) | (yv.y > 0.5f ? 2u : 0u)) << 2;
      code |= ((xv.z > 0.5f ? 1u : 0u) | (yv.z > 0.5f ? 2u : 0u)) << 4;
      code |= ((xv.w > 0.5f ? 1u : 0u) | (yv.w > 0.5f ? 2u : 0u)) << 6;
      sBytes[F] = (uint8_t)code;             // byte F covers cols 4F..4F+3
    }
    if (tid == 0) sCode[256] = 0u;           // clean pad for c==0 warm read
  }

  // ---- phase 2: weights -> LDS, then per-block table build ----
  if (tid < 96) sW1[tid] = W1[tid];
  if (tid < 32) sb1[tid] = b1[tid];
  if (tid < 64) sW2[tid] = W2[tid];
  if (tid < 2)  sb2[tid] = b2[tid];
  __syncthreads();

  for (int e = tid; e < NTAB; e += 256) {
    int xy = e / TBLE, i = e - xy * TBLE;
    float xv = (float)(xy & 1);
    float yv = (float)((xy >> 1) & 1);
    float cv = (float)i * (1.0f / (float)TBLG);
    float s0 = sb2[0], s1 = sb2[1];
    #pragma unroll 8
    for (int j = 0; j < 32; ++j) {
      float z = sb1[j] + xv * sW1[j] + yv * sW1[32 + j] + cv * sW1[64 + j];
      float h = sigmoidf_(z);
      s0 += h * sW2[2 * j];
      s1 += h * sW2[2 * j + 1];
    }
    T[2 * e]     = sigmoidf_(s1);   // out[:,1] -> next carry
    T[2 * e + 1] = sigmoidf_(s0);   // out[:,0] -> sum bit
  }
  __syncthreads();

  // ---- phase 3: serial chunk scan ----
  // chunk c: C0 = 4096-16c-16; own cols = dword 255-c; warm cols = dword 256-c.
  const int c = tid;
  const uint32_t cr = sCode[255 - c];
  const uint32_t cw = sCode[256 - c];        // zero pad for c==0 (unused, guarded)

  float carry = 0.0f;
  if (c > 0) {
    #pragma unroll
    for (int k = 0; k < CHUNK; ++k) {
      unsigned idx = (cw >> (2 * (15 - k))) & 3u;        // col C0+31-k
      float u = fminf(fmaxf(carry * (float)TBLG, 0.0f), (float)(TBLG - 1));
      unsigned iu = (unsigned)u;
      float f = u - (float)iu;
      const float2* p = (const float2*)(T + ((idx * TBLE + iu) << 1));
      float2 lo = p[0], hi = p[1];
      carry = fmaf(f, hi.x - lo.x, lo.x);
    }
  }
  float o[CHUNK];
  #pragma unroll
  for (int k = 0; k < CHUNK; ++k) {
    unsigned idx = (cr >> (2 * (15 - k))) & 3u;          // col C0+15-k
    float u = fminf(fmaxf(carry * (float)TBLG, 0.0f), (float)(TBLG - 1));
    unsigned iu = (unsigned)u;
    float f = u - (float)iu;
    const float2* p = (const float2*)(T + ((idx * TBLE + iu) << 1));
    float2 lo = p[0], hi = p[1];
    carry = fmaf(f, hi.x - lo.x, lo.x);
    o[k]  = fmaf(f, hi.y - lo.y, lo.y);
  }

  // ---- phase 4: stage + coalesced store ----
  {
    float4* fRow4 = (float4*)fRow;
    const int base = (255 - c) * 4;          // float4 index of col C0
    #pragma unroll
    for (int q = 0; q < 4; ++q)
      fRow4[base + q] = make_float4(o[15 - 4*q], o[14 - 4*q], o[13 - 4*q], o[12 - 4*q]);
  }
  __syncthreads();
  {
    float4* out4 = (float4*)(out + (size_t)r * NBITS);
    const float4* fRow4 = (const float4*)fRow;
    #pragma unroll
    for (int q = 0; q < 4; ++q) {
      int F = tid + 256 * q;
      out4[F] = fRow4[F];
    }
  }
}

extern "C" void kernel_launch(void* const* d_in, const int* in_sizes, int n_in,
                              void* d_out, int out_size, void* d_ws, size_t ws_size,
                              hipStream_t stream) {
  const float* x  = (const float*)d_in[0];
  const float* y  = (const float*)d_in[1];
  const float* W1 = (const float*)d_in[2];   // [3][32] row-major
  const float* b1 = (const float*)d_in[3];   // [32]
  const float* W2 = (const float*)d_in[4];   // [32][2] row-major
  const float* b2 = (const float*)d_in[5];   // [2]
  float* out = (float*)d_out;
  (void)d_ws; (void)ws_size; (void)in_sizes; (void)n_in; (void)out_size;

  awc_scan<<<dim3(NROWS), dim3(256), 0, stream>>>(x, y, W1, b1, W2, b2, out);
}

// Round 40
// 30.948 us; speedup vs baseline: 1.4125x; 1.4125x over previous
//
#include <hip/hip_runtime.h>
#include <stdint.h>

#define NBITS 4096
#define NROWS 2048
#define CHUNK 16
#define TBLG  16
#define TBLE  17               // entries per xy case (G+1)
#define NTAB  (4 * TBLE)       // 68 entries
#define TBLN  (NTAB * 2)       // 136 floats (~0.5 KB)

__device__ __forceinline__ float sigmoidf_(float z) {
  return 1.0f / (1.0f + __expf(-z));
}

// Single fused kernel (round-20/23-proven structure), 8x cheaper table build.
// block = one row (256 threads); thread = one 16-bit chunk.
// Phase 1: coalesced load + 2-bit pack into 1KB LDS code array.
// Phase 2: per-block LDS table build — 68 entries, one per thread (tid<68).
// Phase 3: per-thread serial scan (warm-up 16 + real 16) via LDS table lerp.
// Phase 4: per-chunk float4 stores.
__global__ __launch_bounds__(256) void awc_scan(
    const float* __restrict__ x, const float* __restrict__ y,
    const float* __restrict__ W1, const float* __restrict__ b1,
    const float* __restrict__ W2, const float* __restrict__ b2,
    float* __restrict__ out) {
  __shared__ float    sW1[96], sb1[32], sW2[64], sb2[2];
  __shared__ float    T[TBLN];     // interleaved (Tc, To) pairs
  __shared__ uint32_t sCode[260];  // 256 dwords of 2-bit codes (+pad)

  const int tid = threadIdx.x;
  const int r = blockIdx.x;

  // ---- phase 1: coalesced load, pack col j -> bits 2j (x bit | y bit<<1) ----
  {
    const float4* x4 = (const float4*)(x + (size_t)r * NBITS);
    const float4* y4 = (const float4*)(y + (size_t)r * NBITS);
    uint8_t* sBytes = (uint8_t*)sCode;
    #pragma unroll
    for (int q = 0; q < 4; ++q) {
      int F = tid + 256 * q;                 // lanes consecutive -> coalesced
      float4 xv = x4[F], yv = y4[F];
      uint32_t code =  (xv.x > 0.5f ? 1u : 0u) | (yv.x > 0.5f ? 2u : 0u);
      code |= ((xv.y > 0.5f ? 1u : 0u) | (yv.y > 0.5f ? 2u : 0u)) << 2;
      code |= ((xv.z > 0.5f ? 1u : 0u) | (yv.z > 0.5f ? 2u : 0u)) << 4;
      code |= ((xv.w > 0.5f ? 1u : 0u) | (yv.w > 0.5f ? 2u : 0u)) << 6;
      sBytes[F] = (uint8_t)code;             // byte F covers cols 4F..4F+3
    }
    if (tid == 0) sCode[256] = 0u;           // clean pad for c==0 warm read
  }

  // ---- phase 2: weights -> LDS, then 68-entry table (1 entry/thread) ----
  if (tid < 96) sW1[tid] = W1[tid];
  if (tid < 32) sb1[tid] = b1[tid];
  if (tid < 64) sW2[tid] = W2[tid];
  if (tid < 2)  sb2[tid] = b2[tid];
  __syncthreads();

  if (tid < NTAB) {
    const int e = tid;
    const int xy = e / TBLE, i = e - xy * TBLE;
    float xv = (float)(xy & 1);
    float yv = (float)((xy >> 1) & 1);
    float cv = (float)i * (1.0f / (float)TBLG);
    float s0 = sb2[0], s1 = sb2[1];
    #pragma unroll 8
    for (int j = 0; j < 32; ++j) {
      float z = sb1[j] + xv * sW1[j] + yv * sW1[32 + j] + cv * sW1[64 + j];
      float h = sigmoidf_(z);
      s0 += h * sW2[2 * j];
      s1 += h * sW2[2 * j + 1];
    }
    T[2 * e]     = sigmoidf_(s1);   // out[:,1] -> next carry
    T[2 * e + 1] = sigmoidf_(s0);   // out[:,0] -> sum bit
  }
  __syncthreads();

  // ---- phase 3: serial chunk scan ----
  // chunk c: C0 = 4096-16c-16; own cols = dword 255-c; warm = dword 256-c.
  const int c = tid;
  const uint32_t cr = sCode[255 - c];
  const uint32_t cw = sCode[256 - c];        // zero pad for c==0 (guarded)

  float carry = 0.0f;
  if (c > 0) {
    #pragma unroll
    for (int k = 0; k < CHUNK; ++k) {
      unsigned idx = (cw >> (2 * (15 - k))) & 3u;        // col C0+31-k
      float u = fminf(fmaxf(carry * (float)TBLG, 0.0f), (float)(TBLG - 1));
      unsigned iu = (unsigned)u;
      float f = u - (float)iu;
      const float2* p = (const float2*)(T + ((idx * TBLE + iu) << 1));
      float2 lo = p[0], hi = p[1];
      carry = fmaf(f, hi.x - lo.x, lo.x);
    }
  }
  float o[CHUNK];
  #pragma unroll
  for (int k = 0; k < CHUNK; ++k) {
    unsigned idx = (cr >> (2 * (15 - k))) & 3u;          // col C0+15-k
    float u = fminf(fmaxf(carry * (float)TBLG, 0.0f), (float)(TBLG - 1));
    unsigned iu = (unsigned)u;
    float f = u - (float)iu;
    const float2* p = (const float2*)(T + ((idx * TBLE + iu) << 1));
    float2 lo = p[0], hi = p[1];
    carry = fmaf(f, hi.x - lo.x, lo.x);
    o[k]  = fmaf(f, hi.y - lo.y, lo.y);
  }

  // ---- phase 4: store (col C0+15-k -> orow[15-k]) ----
  float* orow = out + (size_t)r * NBITS + (NBITS - CHUNK * c - CHUNK);
  #pragma unroll
  for (int q = 0; q < 4; ++q) {
    ((float4*)orow)[q] = make_float4(o[15 - 4*q], o[14 - 4*q], o[13 - 4*q], o[12 - 4*q]);
  }
}

extern "C" void kernel_launch(void* const* d_in, const int* in_sizes, int n_in,
                              void* d_out, int out_size, void* d_ws, size_t ws_size,
                              hipStream_t stream) {
  const float* x  = (const float*)d_in[0];
  const float* y  = (const float*)d_in[1];
  const float* W1 = (const float*)d_in[2];   // [3][32] row-major
  const float* b1 = (const float*)d_in[3];   // [32]
  const float* W2 = (const float*)d_in[4];   // [32][2] row-major
  const float* b2 = (const float*)d_in[5];   // [2]
  float* out = (float*)d_out;
  (void)d_ws; (void)ws_size; (void)in_sizes; (void)n_in; (void)out_size;

  awc_scan<<<dim3(NROWS), dim3(256), 0, stream>>>(x, y, W1, b1, W2, b2, out);
}